// Round 1
// baseline (397.436 us; speedup 1.0000x reference)
//
#include <hip/hip_runtime.h>

#define IN_CH 48
#define OUT_CH 48
#define BN_EPS 1e-5f

// ---------------------------------------------------------------------------
// k_init: deg[i] = 1.0 (self loop), stats[0..95] = 0
// ---------------------------------------------------------------------------
__global__ void k_init(float* __restrict__ deg, float* __restrict__ stats, int N) {
    int i = blockIdx.x * blockDim.x + threadIdx.x;
    int stride = gridDim.x * blockDim.x;
    for (int j = i; j < N; j += stride) deg[j] = 1.0f;
    if (i < 2 * OUT_CH) stats[i] = 0.0f;
}

// ---------------------------------------------------------------------------
// k_deg: deg[dst[e]] += 1 for each edge
// ---------------------------------------------------------------------------
__global__ void k_deg(const int* __restrict__ dst, float* __restrict__ deg, int E) {
    int i = blockIdx.x * blockDim.x + threadIdx.x;
    int stride = gridDim.x * blockDim.x;
    for (int e = i; e < E; e += stride) atomicAdd(&deg[dst[e]], 1.0f);
}

// ---------------------------------------------------------------------------
// k_gemm: g[i] = (x[i] @ W) * rsqrt(deg[i]);  agg[i] = g[i]  (self-loop init)
// One thread per node; W staged in LDS; x row in registers.
// ---------------------------------------------------------------------------
__global__ __launch_bounds__(256) void k_gemm(const float* __restrict__ x,
                                              const float* __restrict__ W,
                                              const float* __restrict__ deg,
                                              float* __restrict__ g,
                                              float* __restrict__ agg, int N) {
    __shared__ float Wl[IN_CH * OUT_CH];
    for (int idx = threadIdx.x; idx < IN_CH * OUT_CH / 4; idx += blockDim.x)
        ((float4*)Wl)[idx] = ((const float4*)W)[idx];
    __syncthreads();

    int i = blockIdx.x * blockDim.x + threadIdx.x;
    if (i >= N) return;

    float xr[IN_CH];
    const float4* xp = (const float4*)(x + (size_t)i * IN_CH);
#pragma unroll
    for (int k = 0; k < IN_CH / 4; ++k) {
        float4 v = xp[k];
        xr[4 * k] = v.x; xr[4 * k + 1] = v.y; xr[4 * k + 2] = v.z; xr[4 * k + 3] = v.w;
    }
    float di = rsqrtf(deg[i]);

    float4* gp = (float4*)(g + (size_t)i * OUT_CH);
    float4* ap = (float4*)(agg + (size_t)i * OUT_CH);
#pragma unroll 4
    for (int c4 = 0; c4 < OUT_CH / 4; ++c4) {
        float4 acc = make_float4(0.f, 0.f, 0.f, 0.f);
#pragma unroll
        for (int k = 0; k < IN_CH; ++k) {
            float4 w = ((const float4*)Wl)[k * (OUT_CH / 4) + c4];
            acc.x += xr[k] * w.x; acc.y += xr[k] * w.y;
            acc.z += xr[k] * w.z; acc.w += xr[k] * w.w;
        }
        acc.x *= di; acc.y *= di; acc.z *= di; acc.w *= di;
        gp[c4] = acc;
        ap[c4] = acc;
    }
}

// ---------------------------------------------------------------------------
// k_scatter: for each edge e, channel c: agg[dst[e]][c] += g[src[e]][c]
// One thread per (edge, channel): consecutive lanes cover consecutive channels
// of the same edge -> coalesced 192B row reads/atomics.
// ---------------------------------------------------------------------------
__global__ void k_scatter(const int* __restrict__ src, const int* __restrict__ dst,
                          const float* __restrict__ g, float* __restrict__ agg,
                          long long total) {
    long long t = (long long)blockIdx.x * blockDim.x + threadIdx.x;
    long long stride = (long long)gridDim.x * blockDim.x;
    for (; t < total; t += stride) {
        int e = (int)(t / OUT_CH);
        int c = (int)(t - (long long)e * OUT_CH);
        int s = src[e];
        int d = dst[e];
        atomicAdd(&agg[(size_t)d * OUT_CH + c], g[(size_t)s * OUT_CH + c]);
    }
}

// ---------------------------------------------------------------------------
// k_stats: per-channel sum and sum-of-squares of v = agg * dinv
// block = (48, 16); per-ty partials reduced in LDS, then global atomics.
// ---------------------------------------------------------------------------
__global__ __launch_bounds__(768) void k_stats(const float* __restrict__ agg,
                                               const float* __restrict__ deg,
                                               float* __restrict__ stats, int N) {
    __shared__ float ls[16][OUT_CH];
    __shared__ float ls2[16][OUT_CH];
    int c = threadIdx.x;   // 0..47
    int ty = threadIdx.y;  // 0..15
    float s = 0.f, s2 = 0.f;
    for (int r = blockIdx.x * 16 + ty; r < N; r += gridDim.x * 16) {
        float di = rsqrtf(deg[r]);
        float v = agg[(size_t)r * OUT_CH + c] * di;
        s += v;
        s2 += v * v;
    }
    ls[ty][c] = s;
    ls2[ty][c] = s2;
    __syncthreads();
    for (int h = 8; h > 0; h >>= 1) {
        if (ty < h) {
            ls[ty][c] += ls[ty + h][c];
            ls2[ty][c] += ls2[ty + h][c];
        }
        __syncthreads();
    }
    if (ty == 0) {
        atomicAdd(&stats[c], ls[0][c]);
        atomicAdd(&stats[OUT_CH + c], ls2[0][c]);
    }
}

// ---------------------------------------------------------------------------
// k_final: out[j] = relu( (agg[j]*dinv - mean) * rsqrt(var+eps) * gamma + beta )
// In-place on d_out (agg). Bias b cancels under BN mean-subtraction.
// ---------------------------------------------------------------------------
__global__ void k_final(float* __restrict__ out, const float* __restrict__ deg,
                        const float* __restrict__ stats,
                        const float* __restrict__ gamma,
                        const float* __restrict__ beta, int N) {
    int t = blockIdx.x * blockDim.x + threadIdx.x;
    int stride = gridDim.x * blockDim.x;
    float invN = 1.0f / (float)N;
    int total = N * OUT_CH;
    for (int j = t; j < total; j += stride) {
        int r = j / OUT_CH;
        int c = j - r * OUT_CH;
        float v = out[j] * rsqrtf(deg[r]);
        float m = stats[c] * invN;
        float var = stats[OUT_CH + c] * invN - m * m;
        float y = (v - m) * rsqrtf(var + BN_EPS) * gamma[c] + beta[c];
        out[j] = fmaxf(y, 0.0f);
    }
}

extern "C" void kernel_launch(void* const* d_in, const int* in_sizes, int n_in,
                              void* d_out, int out_size, void* d_ws, size_t ws_size,
                              hipStream_t stream) {
    const float* x     = (const float*)d_in[0];
    const int*   ei    = (const int*)d_in[1];
    const float* W     = (const float*)d_in[2];
    // d_in[3] = b : cancels under BatchNorm mean subtraction -> unused
    const float* gamma = (const float*)d_in[4];
    const float* beta  = (const float*)d_in[5];
    float*       out   = (float*)d_out;

    int N = in_sizes[0] / IN_CH;
    int E = in_sizes[1] / 2;
    const int* src = ei;       // edge_index[0]
    const int* dst = ei + E;   // edge_index[1]

    // workspace layout (floats): [0, N): deg/dinv  [N, N+128): stats  [N+128, ...): g
    float* deg   = (float*)d_ws;
    float* stats = deg + N;
    float* g     = deg + N + 128;

    int b256 = 256;

    // 1. init
    k_init<<<(N + b256 - 1) / b256, b256, 0, stream>>>(deg, stats, N);
    // 2. degree (dst-based, self loop already counted via init=1)
    k_deg<<<(E + b256 - 1) / b256, b256, 0, stream>>>(dst, deg, E);
    // 3. g = (x@W)*dinv ; agg(out) = g  (self-loop term)
    k_gemm<<<(N + b256 - 1) / b256, b256, 0, stream>>>(x, W, deg, g, out, N);
    // 4. scatter edges: agg[d] += g[s]
    long long total = (long long)E * OUT_CH;
    long long nblk = (total + b256 - 1) / b256;
    k_scatter<<<(unsigned int)nblk, b256, 0, stream>>>(src, dst, g, out, total);
    // 5. BN stats of v = agg*dinv
    dim3 sblk(OUT_CH, 16);
    k_stats<<<256, sblk, 0, stream>>>(out, deg, stats, N);
    // 6. BN + ReLU in place
    k_final<<<(N * OUT_CH + b256 - 1) / b256, b256, 0, stream>>>(out, deg, stats, gamma, beta, N);
}